// Round 1
// baseline (609.068 us; speedup 1.0000x reference)
//
#include <hip/hip_runtime.h>

#define N_NODES 10000
#define K_COLS 16
#define MEAN_NODES 625.0f

// ws layout (floats): [0..15] = 1/gamma, [16..31] pad, [32..] YT[16][10000]
#define WS_YT_OFF 32

// ---------------------------------------------------------------------------
// Kernel 1: gamma[k] = sum_i Y[i,k]*deg[i]; colsum[k] = sum_i Y[i,k]
// Writes 1/gamma to ws[0..15], error_partition to out[0] (plain store).
// Single workgroup of 256 threads.
// ---------------------------------------------------------------------------
__global__ __launch_bounds__(256) void prep_reduce(const float* __restrict__ Y,
                                                   const float* __restrict__ deg,
                                                   float* __restrict__ ws,
                                                   float* __restrict__ out) {
    const int t = threadIdx.x;
    float g[K_COLS], c[K_COLS];
#pragma unroll
    for (int k = 0; k < K_COLS; ++k) { g[k] = 0.f; c[k] = 0.f; }

    for (int i = t; i < N_NODES; i += 256) {
        float d = deg[i];
        const float4* yp = (const float4*)(Y + (size_t)i * K_COLS);
        float y[K_COLS];
        *(float4*)(y + 0)  = yp[0];
        *(float4*)(y + 4)  = yp[1];
        *(float4*)(y + 8)  = yp[2];
        *(float4*)(y + 12) = yp[3];
#pragma unroll
        for (int k = 0; k < K_COLS; ++k) { g[k] += y[k] * d; c[k] += y[k]; }
    }

    // wave-level reduction (64 lanes)
#pragma unroll
    for (int k = 0; k < K_COLS; ++k) {
        for (int off = 32; off > 0; off >>= 1) {
            g[k] += __shfl_down(g[k], off);
            c[k] += __shfl_down(c[k], off);
        }
    }

    __shared__ float red[4][32];
    const int wave = t >> 6, lane = t & 63;
    if (lane == 0) {
#pragma unroll
        for (int k = 0; k < K_COLS; ++k) {
            red[wave][k] = g[k];
            red[wave][K_COLS + k] = c[k];
        }
    }
    __syncthreads();

    if (t < 32) {
        float v = red[0][t] + red[1][t] + red[2][t] + red[3][t];
        if (t < 16) {
            ws[t] = 1.0f / v;   // rgamma
        } else {
            float dlt = v - MEAN_NODES;
            float sq = dlt * dlt;
            // reduce over threads 16..31 (subgroup of width 16 inside wave 0)
            for (int off = 8; off > 0; off >>= 1) sq += __shfl_down(sq, off, 16);
            if (t == 16) out[0] = sq;   // error_partition; error_cut added later
        }
    }
}

// ---------------------------------------------------------------------------
// Kernel 2: transpose Y [10000,16] -> YT [16][10000] in ws (L2-resident copy)
// ---------------------------------------------------------------------------
__global__ __launch_bounds__(256) void prep_transpose(const float* __restrict__ Y,
                                                      float* __restrict__ yt) {
    const int i = blockIdx.x * 256 + threadIdx.x;
    if (i < N_NODES) {
        const float4* yp = (const float4*)(Y + (size_t)i * K_COLS);
        float y[K_COLS];
        *(float4*)(y + 0)  = yp[0];
        *(float4*)(y + 4)  = yp[1];
        *(float4*)(y + 8)  = yp[2];
        *(float4*)(y + 12) = yp[3];
#pragma unroll
        for (int k = 0; k < K_COLS; ++k) yt[(size_t)k * N_NODES + i] = y[k];
    }
}

// ---------------------------------------------------------------------------
// Kernel 3 (hot): error_cut = sum_ij A_ij*(s_i - Yn_i . Y_j)
//   = sum_i s_i * rowsumA_i - sum_{i,k} Yn[i,k] * (A@Y)[i,k]
// Each wave: 4 rows; each lane: 4 consecutive j per step (float4 loads of A
// and of YT). acc[r][k] accumulates (A@Y) partials; rowsum[r] the A row sums.
// Epilogue contracts with Yn (computed on the fly from Y and 1/gamma) and
// atomicAdds one scalar per workgroup.
// grid = (625 row-blocks of 16, 5 j-segments of 8*256 j-steps)
// ---------------------------------------------------------------------------
#define STEPS_PER_SEG 8

__global__ __launch_bounds__(256) void gap_main(const float* __restrict__ A,
                                                const float* __restrict__ Y,
                                                const float* __restrict__ ws,
                                                float* __restrict__ out) {
    const float* __restrict__ YT = ws + WS_YT_OFF;
    const int wave = threadIdx.x >> 6;
    const int lane = threadIdx.x & 63;
    const int rowbase = blockIdx.x * 16 + wave * 4;

    float acc[4][K_COLS];
    float rowsum[4];
#pragma unroll
    for (int r = 0; r < 4; ++r) {
        rowsum[r] = 0.f;
#pragma unroll
        for (int k = 0; k < K_COLS; ++k) acc[r][k] = 0.f;
    }

    const int stepbase = blockIdx.y * STEPS_PER_SEG;
    const size_t arow_off = (size_t)rowbase * N_NODES;

#pragma unroll 1
    for (int s = 0; s < STEPS_PER_SEG; ++s) {
        const int j0 = ((stepbase + s) << 8) + (lane << 2);
        if (j0 < N_NODES) {   // N%4==0 so any in-range j0 has a full float4
            const float* arow = A + arow_off + j0;
            const float4 a0 = *(const float4*)(arow);
            const float4 a1 = *(const float4*)(arow + N_NODES);
            const float4 a2 = *(const float4*)(arow + 2 * (size_t)N_NODES);
            const float4 a3 = *(const float4*)(arow + 3 * (size_t)N_NODES);

            rowsum[0] += (a0.x + a0.y) + (a0.z + a0.w);
            rowsum[1] += (a1.x + a1.y) + (a1.z + a1.w);
            rowsum[2] += (a2.x + a2.y) + (a2.z + a2.w);
            rowsum[3] += (a3.x + a3.y) + (a3.z + a3.w);

            const float* ytp = YT + j0;
#pragma unroll
            for (int k = 0; k < K_COLS; ++k) {
                const float4 y = *(const float4*)(ytp + (size_t)k * N_NODES);
                acc[0][k] += a0.x * y.x + a0.y * y.y + a0.z * y.z + a0.w * y.w;
                acc[1][k] += a1.x * y.x + a1.y * y.y + a1.z * y.z + a1.w * y.w;
                acc[2][k] += a2.x * y.x + a2.y * y.y + a2.z * y.z + a2.w * y.w;
                acc[3][k] += a3.x * y.x + a3.y * y.y + a3.z * y.z + a3.w * y.w;
            }
        }
    }

    // epilogue: partial = sum_r [ s_i * rowsum[r] - sum_k Yn[i,k]*acc[r][k] ]
    __shared__ float rgs[K_COLS];
    if (threadIdx.x < K_COLS) rgs[threadIdx.x] = ws[threadIdx.x];
    __syncthreads();

    float partial = 0.f;
#pragma unroll
    for (int r = 0; r < 4; ++r) {
        const int row = rowbase + r;
        const float* yrow = Y + (size_t)row * K_COLS;
        float s_i = 0.f, dotv = 0.f;
#pragma unroll
        for (int k = 0; k < K_COLS; ++k) {
            const float yn = yrow[k] * rgs[k];  // Yn[row][k]
            s_i += yn;
            dotv += yn * acc[r][k];
        }
        partial += s_i * rowsum[r] - dotv;
    }

    // wave reduce, then block reduce, then one atomic per WG
    for (int off = 32; off > 0; off >>= 1) partial += __shfl_down(partial, off);
    __shared__ float wpart[4];
    if (lane == 0) wpart[wave] = partial;
    __syncthreads();
    if (threadIdx.x == 0)
        atomicAdd(out, (wpart[0] + wpart[1]) + (wpart[2] + wpart[3]));
}

// ---------------------------------------------------------------------------
extern "C" void kernel_launch(void* const* d_in, const int* in_sizes, int n_in,
                              void* d_out, int out_size, void* d_ws, size_t ws_size,
                              hipStream_t stream) {
    const float* Y   = (const float*)d_in[0];   // [10000,16]
    const float* A   = (const float*)d_in[1];   // [10000,10000]
    const float* deg = (const float*)d_in[2];   // [10000,1]
    float* out = (float*)d_out;                 // scalar
    float* ws  = (float*)d_ws;                  // >= (32 + 16*10000) floats

    hipLaunchKernelGGL(prep_reduce, dim3(1), dim3(256), 0, stream, Y, deg, ws, out);
    hipLaunchKernelGGL(prep_transpose, dim3((N_NODES + 255) / 256), dim3(256), 0, stream,
                       Y, ws + WS_YT_OFF);
    hipLaunchKernelGGL(gap_main, dim3(N_NODES / 16, 5), dim3(256), 0, stream,
                       A, Y, ws, out);
}

// Round 2
// 564.417 us; speedup vs baseline: 1.0791x; 1.0791x over previous
//
#include <hip/hip_runtime.h>

#define N_NODES 10000
#define K_COLS 16
#define MEAN_NODES 625.0f

// ws layout (floats):
//   [0..15]                : 1/gamma (written by prep_final)
//   [64 .. 64+40*32)       : per-block partials (40 blocks x {16 gamma, 16 colsum})
//   [4096 .. 4096+160000)  : YT[16][10000] transposed Y
#define WS_PART_OFF 64
#define WS_YT_OFF 4096
#define PREP_BLOCKS 40   // 40 * 250 = 10000 rows

// ---------------------------------------------------------------------------
// Kernel 1: per-block partial gamma/colsum + fused transpose of Y.
// Block b handles rows [b*250, b*250+250). One row per thread.
// ---------------------------------------------------------------------------
__global__ __launch_bounds__(256) void prep_partial(const float* __restrict__ Y,
                                                    const float* __restrict__ deg,
                                                    float* __restrict__ ws) {
    const int b = blockIdx.x;
    const int t = threadIdx.x;
    const int i = b * 250 + t;
    const bool valid = (t < 250);

    float y[K_COLS];
    float d = 0.f;
    if (valid) {
        d = deg[i];
        const float4* yp = (const float4*)(Y + (size_t)i * K_COLS);
        *(float4*)(y + 0)  = yp[0];
        *(float4*)(y + 4)  = yp[1];
        *(float4*)(y + 8)  = yp[2];
        *(float4*)(y + 12) = yp[3];
        float* yt = ws + WS_YT_OFF;
#pragma unroll
        for (int k = 0; k < K_COLS; ++k) yt[(size_t)k * N_NODES + i] = y[k];
    } else {
#pragma unroll
        for (int k = 0; k < K_COLS; ++k) y[k] = 0.f;
    }

    float g[K_COLS], c[K_COLS];
#pragma unroll
    for (int k = 0; k < K_COLS; ++k) { g[k] = y[k] * d; c[k] = y[k]; }

    // wave-level reduction (64 lanes)
#pragma unroll
    for (int k = 0; k < K_COLS; ++k) {
        for (int off = 32; off > 0; off >>= 1) {
            g[k] += __shfl_down(g[k], off);
            c[k] += __shfl_down(c[k], off);
        }
    }

    __shared__ float red[4][32];
    const int wave = t >> 6, lane = t & 63;
    if (lane == 0) {
#pragma unroll
        for (int k = 0; k < K_COLS; ++k) {
            red[wave][k] = g[k];
            red[wave][K_COLS + k] = c[k];
        }
    }
    __syncthreads();

    if (t < 32) {
        float v = red[0][t] + red[1][t] + red[2][t] + red[3][t];
        ws[WS_PART_OFF + b * 32 + t] = v;
    }
}

// ---------------------------------------------------------------------------
// Kernel 2: finalize — sum the 40 partials; 1/gamma -> ws[0..15];
// error_partition -> out[0] (plain store; gap_main atomicAdds on top).
// ---------------------------------------------------------------------------
__global__ __launch_bounds__(64) void prep_final(float* __restrict__ ws,
                                                 float* __restrict__ out) {
    const int t = threadIdx.x;
    if (t < 32) {
        float v = 0.f;
#pragma unroll
        for (int b = 0; b < PREP_BLOCKS; ++b) v += ws[WS_PART_OFF + b * 32 + t];
        if (t < 16) {
            ws[t] = 1.0f / v;   // rgamma
        } else {
            float dlt = v - MEAN_NODES;
            float sq = dlt * dlt;
            for (int off = 8; off > 0; off >>= 1) sq += __shfl_down(sq, off, 16);
            if (t == 16) out[0] = sq;
        }
    }
}

// ---------------------------------------------------------------------------
// Kernel 3 (hot): error_cut = sum_i s_i*rowsumA_i - sum_{i,k} Yn[i,k]*(A@Y)[i,k]
// Wave: 4 rows; lane: 4 consecutive j per step. Explicit one-step software
// pipeline on the A loads (HBM ~900 cyc latency) so the next step's A tile is
// in flight during this step's 256 FMAs. Invalid lanes (j >= N) get clamped
// addresses and zeroed A values — no branch in the hot loop.
// grid = (625 row-blocks of 16, 5 j-segments of 8 steps x 256 j)
// ---------------------------------------------------------------------------
#define STEPS_PER_SEG 8

__global__ __launch_bounds__(256) void gap_main(const float* __restrict__ A,
                                                const float* __restrict__ Y,
                                                const float* __restrict__ ws,
                                                float* __restrict__ out) {
    const float* __restrict__ YT = ws + WS_YT_OFF;
    const int wave = threadIdx.x >> 6;
    const int lane = threadIdx.x & 63;
    const int rowbase = blockIdx.x * 16 + wave * 4;

    float acc[4][K_COLS];
    float rowsum[4];
#pragma unroll
    for (int r = 0; r < 4; ++r) {
        rowsum[r] = 0.f;
#pragma unroll
        for (int k = 0; k < K_COLS; ++k) acc[r][k] = 0.f;
    }

    const float* __restrict__ Abase = A + (size_t)rowbase * N_NODES;
    const int jstart = (blockIdx.y * STEPS_PER_SEG << 8) + (lane << 2);

    // --- prologue: load step 0's A tile ---
    bool v_cur = jstart < N_NODES;
    int jc_cur = v_cur ? jstart : 0;
    float4 a0, a1, a2, a3;
    {
        const float* p = Abase + jc_cur;
        a0 = *(const float4*)(p);
        a1 = *(const float4*)(p + N_NODES);
        a2 = *(const float4*)(p + 2 * (size_t)N_NODES);
        a3 = *(const float4*)(p + 3 * (size_t)N_NODES);
        if (!v_cur) {
            a0 = a1 = a2 = a3 = make_float4(0.f, 0.f, 0.f, 0.f);
        }
    }

#pragma unroll 1
    for (int s = 0; s < STEPS_PER_SEG; ++s) {
        // --- prefetch step s+1's A tile ---
        const int jnext = jstart + ((s + 1) << 8);
        const bool v_next = (s + 1 < STEPS_PER_SEG) && (jnext < N_NODES);
        const int jc_next = v_next ? jnext : 0;
        const float* pn = Abase + jc_next;
        float4 b0 = *(const float4*)(pn);
        float4 b1 = *(const float4*)(pn + N_NODES);
        float4 b2 = *(const float4*)(pn + 2 * (size_t)N_NODES);
        float4 b3 = *(const float4*)(pn + 3 * (size_t)N_NODES);
        if (!v_next) {
            b0 = b1 = b2 = b3 = make_float4(0.f, 0.f, 0.f, 0.f);
        }

        // --- compute with current A tile ---
        rowsum[0] += (a0.x + a0.y) + (a0.z + a0.w);
        rowsum[1] += (a1.x + a1.y) + (a1.z + a1.w);
        rowsum[2] += (a2.x + a2.y) + (a2.z + a2.w);
        rowsum[3] += (a3.x + a3.y) + (a3.z + a3.w);

        const float* ytp = YT + jc_cur;
#pragma unroll
        for (int k = 0; k < K_COLS; ++k) {
            const float4 y = *(const float4*)(ytp + (size_t)k * N_NODES);
            acc[0][k] += a0.x * y.x + a0.y * y.y + a0.z * y.z + a0.w * y.w;
            acc[1][k] += a1.x * y.x + a1.y * y.y + a1.z * y.z + a1.w * y.w;
            acc[2][k] += a2.x * y.x + a2.y * y.y + a2.z * y.z + a2.w * y.w;
            acc[3][k] += a3.x * y.x + a3.y * y.y + a3.z * y.z + a3.w * y.w;
        }

        // --- rotate pipeline ---
        a0 = b0; a1 = b1; a2 = b2; a3 = b3;
        jc_cur = jc_next;
    }

    // epilogue: partial = sum_r [ s_i * rowsum[r] - sum_k Yn[i,k]*acc[r][k] ]
    __shared__ float rgs[K_COLS];
    if (threadIdx.x < K_COLS) rgs[threadIdx.x] = ws[threadIdx.x];
    __syncthreads();

    float partial = 0.f;
#pragma unroll
    for (int r = 0; r < 4; ++r) {
        const int row = rowbase + r;
        const float* yrow = Y + (size_t)row * K_COLS;
        float s_i = 0.f, dotv = 0.f;
#pragma unroll
        for (int k = 0; k < K_COLS; ++k) {
            const float yn = yrow[k] * rgs[k];  // Yn[row][k]
            s_i += yn;
            dotv += yn * acc[r][k];
        }
        partial += s_i * rowsum[r] - dotv;
    }

    for (int off = 32; off > 0; off >>= 1) partial += __shfl_down(partial, off);
    __shared__ float wpart[4];
    if (lane == 0) wpart[wave] = partial;
    __syncthreads();
    if (threadIdx.x == 0)
        atomicAdd(out, (wpart[0] + wpart[1]) + (wpart[2] + wpart[3]));
}

// ---------------------------------------------------------------------------
extern "C" void kernel_launch(void* const* d_in, const int* in_sizes, int n_in,
                              void* d_out, int out_size, void* d_ws, size_t ws_size,
                              hipStream_t stream) {
    const float* Y   = (const float*)d_in[0];   // [10000,16]
    const float* A   = (const float*)d_in[1];   // [10000,10000]
    const float* deg = (const float*)d_in[2];   // [10000,1]
    float* out = (float*)d_out;                 // scalar
    float* ws  = (float*)d_ws;

    hipLaunchKernelGGL(prep_partial, dim3(PREP_BLOCKS), dim3(256), 0, stream, Y, deg, ws);
    hipLaunchKernelGGL(prep_final, dim3(1), dim3(64), 0, stream, ws, out);
    hipLaunchKernelGGL(gap_main, dim3(N_NODES / 16, 5), dim3(256), 0, stream,
                       A, Y, ws, out);
}

// Round 3
// 538.445 us; speedup vs baseline: 1.1312x; 1.0482x over previous
//
#include <hip/hip_runtime.h>

#define N_NODES 10000
#define K_COLS 16
#define MEAN_NODES 625.0f

// ws layout (floats):
//   [0..15]           : 1/gamma (written by prep_final)
//   [64 .. 64+40*32)  : per-block partials (40 blocks x {16 gamma, 16 colsum})
#define WS_PART_OFF 64
#define PREP_BLOCKS 40

// ---------------------------------------------------------------------------
// Kernel 1: per-block partial gamma/colsum. Block b: rows [b*250, b*250+250).
// ---------------------------------------------------------------------------
__global__ __launch_bounds__(256) void prep_partial(const float* __restrict__ Y,
                                                    const float* __restrict__ deg,
                                                    float* __restrict__ ws) {
    const int b = blockIdx.x;
    const int t = threadIdx.x;
    const int i = b * 250 + t;
    const bool valid = (t < 250);

    float y[K_COLS];
    float d = 0.f;
    if (valid) {
        d = deg[i];
        const float4* yp = (const float4*)(Y + (size_t)i * K_COLS);
        *(float4*)(y + 0)  = yp[0];
        *(float4*)(y + 4)  = yp[1];
        *(float4*)(y + 8)  = yp[2];
        *(float4*)(y + 12) = yp[3];
    } else {
#pragma unroll
        for (int k = 0; k < K_COLS; ++k) y[k] = 0.f;
    }

    float g[K_COLS], c[K_COLS];
#pragma unroll
    for (int k = 0; k < K_COLS; ++k) { g[k] = y[k] * d; c[k] = y[k]; }

#pragma unroll
    for (int k = 0; k < K_COLS; ++k) {
        for (int off = 32; off > 0; off >>= 1) {
            g[k] += __shfl_down(g[k], off);
            c[k] += __shfl_down(c[k], off);
        }
    }

    __shared__ float red[4][32];
    const int wave = t >> 6, lane = t & 63;
    if (lane == 0) {
#pragma unroll
        for (int k = 0; k < K_COLS; ++k) {
            red[wave][k] = g[k];
            red[wave][K_COLS + k] = c[k];
        }
    }
    __syncthreads();

    if (t < 32) {
        float v = red[0][t] + red[1][t] + red[2][t] + red[3][t];
        ws[WS_PART_OFF + b * 32 + t] = v;
    }
}

// ---------------------------------------------------------------------------
// Kernel 2: finalize — 1/gamma -> ws[0..15]; error_partition -> out[0].
// ---------------------------------------------------------------------------
__global__ __launch_bounds__(64) void prep_final(float* __restrict__ ws,
                                                 float* __restrict__ out) {
    const int t = threadIdx.x;
    if (t < 32) {
        float v = 0.f;
#pragma unroll
        for (int b = 0; b < PREP_BLOCKS; ++b) v += ws[WS_PART_OFF + b * 32 + t];
        if (t < 16) {
            ws[t] = 1.0f / v;   // rgamma
        } else {
            float dlt = v - MEAN_NODES;
            float sq = dlt * dlt;
            for (int off = 8; off > 0; off >>= 1) sq += __shfl_down(sq, off, 16);
            if (t == 16) out[0] = sq;
        }
    }
}

// ---------------------------------------------------------------------------
// Kernel 3 (hot), column-major accumulation:
//   error_cut = sum_j r_j - sum_{j,k} D[j,k]*Y[j,k],   D = A^T @ Yn,
//   r_j = sum_i A_ij * s_i,  s_i = sum_k Yn[i,k].
// Thread t owns 4 consecutive columns j = jtile*1024 + 4t. Per row i it loads
// one float4 of A (only vector-memory traffic: 1 KB/wave-step) and the
// wave-uniform Yn_i[16], s_i from LDS (broadcast — conflict-free, separate
// pipe). Depth-2 prefetch on A, unroll 2. Lanes with j >= N clamp the address
// and are masked in the epilogue only.
// grid = (10 j-tiles, 100 row-segments of 100 rows)
// ---------------------------------------------------------------------------
#define ROWS_PER_SEG 100
#define JT_WIDTH 1024

__device__ __forceinline__ void accum_row(const float4 a, const float* __restrict__ ynrow,
                                          const float si,
                                          float d[4][K_COLS], float r[4]) {
    const float av0 = a.x, av1 = a.y, av2 = a.z, av3 = a.w;
    r[0] += av0 * si; r[1] += av1 * si; r[2] += av2 * si; r[3] += av3 * si;
    float yn[K_COLS];
    *(float4*)(yn + 0)  = *(const float4*)(ynrow + 0);
    *(float4*)(yn + 4)  = *(const float4*)(ynrow + 4);
    *(float4*)(yn + 8)  = *(const float4*)(ynrow + 8);
    *(float4*)(yn + 12) = *(const float4*)(ynrow + 12);
#pragma unroll
    for (int k = 0; k < K_COLS; ++k) {
        d[0][k] += av0 * yn[k];
        d[1][k] += av1 * yn[k];
        d[2][k] += av2 * yn[k];
        d[3][k] += av3 * yn[k];
    }
}

__global__ __launch_bounds__(256, 3) void gap_main(const float* __restrict__ A,
                                                   const float* __restrict__ Y,
                                                   const float* __restrict__ ws,
                                                   float* __restrict__ out) {
    __shared__ float YnL[ROWS_PER_SEG][K_COLS];
    __shared__ float sL[ROWS_PER_SEG];

    const int t = threadIdx.x;
    const int i0 = blockIdx.y * ROWS_PER_SEG;
    const int j0 = blockIdx.x * JT_WIDTH + (t << 2);
    const bool jvalid = j0 < N_NODES;
    const int jc = jvalid ? j0 : (N_NODES - 4);

    // stage Yn rows + s for this row segment
    if (t < ROWS_PER_SEG) {
        const float* yrow = Y + (size_t)(i0 + t) * K_COLS;
        float yn[K_COLS];
        float s = 0.f;
#pragma unroll
        for (int k = 0; k < K_COLS; ++k) {
            yn[k] = yrow[k] * ws[k];
            s += yn[k];
        }
#pragma unroll
        for (int k = 0; k < K_COLS; ++k) YnL[t][k] = yn[k];
        sL[t] = s;
    }
    __syncthreads();

    float d[4][K_COLS];
    float r[4] = {0.f, 0.f, 0.f, 0.f};
#pragma unroll
    for (int jj = 0; jj < 4; ++jj)
#pragma unroll
        for (int k = 0; k < K_COLS; ++k) d[jj][k] = 0.f;

    const float* __restrict__ Ab = A + (size_t)i0 * N_NODES + jc;

    // depth-2 pipeline, unroll 2 over rows
    float4 a0 = *(const float4*)(Ab);
    float4 a1 = *(const float4*)(Ab + N_NODES);

#pragma unroll 1
    for (int ii = 0; ii < ROWS_PER_SEG; ii += 2) {
        const int n2 = (ii + 2 < ROWS_PER_SEG) ? ii + 2 : ROWS_PER_SEG - 1;
        const int n3 = (ii + 3 < ROWS_PER_SEG) ? ii + 3 : ROWS_PER_SEG - 1;
        const float4 p0 = *(const float4*)(Ab + (size_t)n2 * N_NODES);
        const float4 p1 = *(const float4*)(Ab + (size_t)n3 * N_NODES);

        accum_row(a0, &YnL[ii][0],     sL[ii],     d, r);
        accum_row(a1, &YnL[ii + 1][0], sL[ii + 1], d, r);

        a0 = p0; a1 = p1;
    }

    // epilogue: partial = sum_jj [ r_jj - sum_k d[jj][k]*Y[j0+jj][k] ]
    float partial = 0.f;
    if (jvalid) {
#pragma unroll
        for (int jj = 0; jj < 4; ++jj) {
            const float* yj = Y + (size_t)(j0 + jj) * K_COLS;
            float yv[K_COLS];
            *(float4*)(yv + 0)  = *(const float4*)(yj + 0);
            *(float4*)(yv + 4)  = *(const float4*)(yj + 4);
            *(float4*)(yv + 8)  = *(const float4*)(yj + 8);
            *(float4*)(yv + 12) = *(const float4*)(yj + 12);
            float dot = 0.f;
#pragma unroll
            for (int k = 0; k < K_COLS; ++k) dot += d[jj][k] * yv[k];
            partial += r[jj] - dot;
        }
    }

    for (int off = 32; off > 0; off >>= 1) partial += __shfl_down(partial, off);
    __shared__ float wpart[4];
    const int wave = t >> 6, lane = t & 63;
    if (lane == 0) wpart[wave] = partial;
    __syncthreads();
    if (t == 0)
        atomicAdd(out, (wpart[0] + wpart[1]) + (wpart[2] + wpart[3]));
}

// ---------------------------------------------------------------------------
extern "C" void kernel_launch(void* const* d_in, const int* in_sizes, int n_in,
                              void* d_out, int out_size, void* d_ws, size_t ws_size,
                              hipStream_t stream) {
    const float* Y   = (const float*)d_in[0];   // [10000,16]
    const float* A   = (const float*)d_in[1];   // [10000,10000]
    const float* deg = (const float*)d_in[2];   // [10000,1]
    float* out = (float*)d_out;                 // scalar
    float* ws  = (float*)d_ws;

    hipLaunchKernelGGL(prep_partial, dim3(PREP_BLOCKS), dim3(256), 0, stream, Y, deg, ws);
    hipLaunchKernelGGL(prep_final, dim3(1), dim3(64), 0, stream, ws, out);
    hipLaunchKernelGGL(gap_main, dim3(10, 100), dim3(256), 0, stream, A, Y, ws, out);
}

// Round 4
// 502.830 us; speedup vs baseline: 1.2113x; 1.0708x over previous
//
#include <hip/hip_runtime.h>

#define N_NODES 10000
#define K_COLS 16
#define MEAN_NODES 625.0f

// ws layout (floats):
//   [0..15]           : 1/gamma (written by prep_final)
//   [64 .. 64+40*32)  : per-block partials (40 blocks x {16 gamma, 16 colsum})
#define WS_PART_OFF 64
#define PREP_BLOCKS 40

typedef float vf4 __attribute__((ext_vector_type(4)));

// ---------------------------------------------------------------------------
// Kernel 1: per-block partial gamma/colsum. Block b: rows [b*250, b*250+250).
// ---------------------------------------------------------------------------
__global__ __launch_bounds__(256) void prep_partial(const float* __restrict__ Y,
                                                    const float* __restrict__ deg,
                                                    float* __restrict__ ws) {
    const int b = blockIdx.x;
    const int t = threadIdx.x;
    const int i = b * 250 + t;
    const bool valid = (t < 250);

    float y[K_COLS];
    float d = 0.f;
    if (valid) {
        d = deg[i];
        const float4* yp = (const float4*)(Y + (size_t)i * K_COLS);
        *(float4*)(y + 0)  = yp[0];
        *(float4*)(y + 4)  = yp[1];
        *(float4*)(y + 8)  = yp[2];
        *(float4*)(y + 12) = yp[3];
    } else {
#pragma unroll
        for (int k = 0; k < K_COLS; ++k) y[k] = 0.f;
    }

    float g[K_COLS], c[K_COLS];
#pragma unroll
    for (int k = 0; k < K_COLS; ++k) { g[k] = y[k] * d; c[k] = y[k]; }

#pragma unroll
    for (int k = 0; k < K_COLS; ++k) {
        for (int off = 32; off > 0; off >>= 1) {
            g[k] += __shfl_down(g[k], off);
            c[k] += __shfl_down(c[k], off);
        }
    }

    __shared__ float red[4][32];
    const int wave = t >> 6, lane = t & 63;
    if (lane == 0) {
#pragma unroll
        for (int k = 0; k < K_COLS; ++k) {
            red[wave][k] = g[k];
            red[wave][K_COLS + k] = c[k];
        }
    }
    __syncthreads();

    if (t < 32) {
        float v = red[0][t] + red[1][t] + red[2][t] + red[3][t];
        ws[WS_PART_OFF + b * 32 + t] = v;
    }
}

// ---------------------------------------------------------------------------
// Kernel 2: finalize — 1/gamma -> ws[0..15]; error_partition -> out[0].
// ---------------------------------------------------------------------------
__global__ __launch_bounds__(64) void prep_final(float* __restrict__ ws,
                                                 float* __restrict__ out) {
    const int t = threadIdx.x;
    if (t < 32) {
        float v = 0.f;
#pragma unroll
        for (int b = 0; b < PREP_BLOCKS; ++b) v += ws[WS_PART_OFF + b * 32 + t];
        if (t < 16) {
            ws[t] = 1.0f / v;   // rgamma
        } else {
            float dlt = v - MEAN_NODES;
            float sq = dlt * dlt;
            for (int off = 8; off > 0; off >>= 1) sq += __shfl_down(sq, off, 16);
            if (t == 16) out[0] = sq;
        }
    }
}

// ---------------------------------------------------------------------------
// Kernel 3 (hot), column-major accumulation:
//   error_cut = sum_j r_j - sum_{j,k} D[j,k]*Y[j,k],   D = A^T @ Yn,
//   r_j = sum_i A_ij * s_i,  s_i = sum_k Yn[i,k].
// Thread t owns 4 consecutive columns j. Per row i: one nt float4 of A
// (only VMEM traffic) + wave-uniform Yn_i[16], s_i broadcast from LDS.
// Depth-2 prefetch, unroll 2. launch_bounds(256,4): 4 blocks/CU so the
// 1000-block grid is a single dispatch wave (tail ~2%) and 16 waves/CU
// cover the ~900-cyc HBM latency.
// grid = (10 j-tiles, 100 row-segments of 100 rows)
// ---------------------------------------------------------------------------
#define ROWS_PER_SEG 100
#define JT_WIDTH 1024

__device__ __forceinline__ void accum_row(const vf4 a, const float* __restrict__ ynrow,
                                          const float si,
                                          float d[4][K_COLS], float r[4]) {
    const float av0 = a.x, av1 = a.y, av2 = a.z, av3 = a.w;
    r[0] += av0 * si; r[1] += av1 * si; r[2] += av2 * si; r[3] += av3 * si;
    float yn[K_COLS];
    *(float4*)(yn + 0)  = *(const float4*)(ynrow + 0);
    *(float4*)(yn + 4)  = *(const float4*)(ynrow + 4);
    *(float4*)(yn + 8)  = *(const float4*)(ynrow + 8);
    *(float4*)(yn + 12) = *(const float4*)(ynrow + 12);
#pragma unroll
    for (int k = 0; k < K_COLS; ++k) {
        d[0][k] += av0 * yn[k];
        d[1][k] += av1 * yn[k];
        d[2][k] += av2 * yn[k];
        d[3][k] += av3 * yn[k];
    }
}

__global__ __launch_bounds__(256, 4) void gap_main(const float* __restrict__ A,
                                                   const float* __restrict__ Y,
                                                   const float* __restrict__ ws,
                                                   float* __restrict__ out) {
    __shared__ float YnL[ROWS_PER_SEG][K_COLS];
    __shared__ float sL[ROWS_PER_SEG];

    const int t = threadIdx.x;
    const int i0 = blockIdx.y * ROWS_PER_SEG;
    const int j0 = blockIdx.x * JT_WIDTH + (t << 2);
    const bool jvalid = j0 < N_NODES;
    const int jc = jvalid ? j0 : (N_NODES - 4);

    // stage Yn rows + s for this row segment
    if (t < ROWS_PER_SEG) {
        const float* yrow = Y + (size_t)(i0 + t) * K_COLS;
        float yn[K_COLS];
        float s = 0.f;
#pragma unroll
        for (int k = 0; k < K_COLS; ++k) {
            yn[k] = yrow[k] * ws[k];
            s += yn[k];
        }
#pragma unroll
        for (int k = 0; k < K_COLS; ++k) YnL[t][k] = yn[k];
        sL[t] = s;
    }
    __syncthreads();

    float d[4][K_COLS];
    float r[4] = {0.f, 0.f, 0.f, 0.f};
#pragma unroll
    for (int jj = 0; jj < 4; ++jj)
#pragma unroll
        for (int k = 0; k < K_COLS; ++k) d[jj][k] = 0.f;

    const float* __restrict__ Ab = A + (size_t)i0 * N_NODES + jc;

    // depth-2 pipeline, unroll 2 over rows, non-temporal A stream
    vf4 a0 = __builtin_nontemporal_load((const vf4*)(Ab));
    vf4 a1 = __builtin_nontemporal_load((const vf4*)(Ab + N_NODES));

#pragma unroll 1
    for (int ii = 0; ii < ROWS_PER_SEG; ii += 2) {
        const int n2 = (ii + 2 < ROWS_PER_SEG) ? ii + 2 : ROWS_PER_SEG - 1;
        const int n3 = (ii + 3 < ROWS_PER_SEG) ? ii + 3 : ROWS_PER_SEG - 1;
        const vf4 p0 = __builtin_nontemporal_load((const vf4*)(Ab + (size_t)n2 * N_NODES));
        const vf4 p1 = __builtin_nontemporal_load((const vf4*)(Ab + (size_t)n3 * N_NODES));

        accum_row(a0, &YnL[ii][0],     sL[ii],     d, r);
        accum_row(a1, &YnL[ii + 1][0], sL[ii + 1], d, r);

        a0 = p0; a1 = p1;
    }

    // epilogue: partial = sum_jj [ r_jj - sum_k d[jj][k]*Y[j0+jj][k] ]
    float partial = 0.f;
    if (jvalid) {
#pragma unroll
        for (int jj = 0; jj < 4; ++jj) {
            const float* yj = Y + (size_t)(j0 + jj) * K_COLS;
            float yv[K_COLS];
            *(float4*)(yv + 0)  = *(const float4*)(yj + 0);
            *(float4*)(yv + 4)  = *(const float4*)(yj + 4);
            *(float4*)(yv + 8)  = *(const float4*)(yj + 8);
            *(float4*)(yv + 12) = *(const float4*)(yj + 12);
            float dot = 0.f;
#pragma unroll
            for (int k = 0; k < K_COLS; ++k) dot += d[jj][k] * yv[k];
            partial += r[jj] - dot;
        }
    }

    for (int off = 32; off > 0; off >>= 1) partial += __shfl_down(partial, off);
    __shared__ float wpart[4];
    const int wave = t >> 6, lane = t & 63;
    if (lane == 0) wpart[wave] = partial;
    __syncthreads();
    if (t == 0)
        atomicAdd(out, (wpart[0] + wpart[1]) + (wpart[2] + wpart[3]));
}

// ---------------------------------------------------------------------------
extern "C" void kernel_launch(void* const* d_in, const int* in_sizes, int n_in,
                              void* d_out, int out_size, void* d_ws, size_t ws_size,
                              hipStream_t stream) {
    const float* Y   = (const float*)d_in[0];   // [10000,16]
    const float* A   = (const float*)d_in[1];   // [10000,10000]
    const float* deg = (const float*)d_in[2];   // [10000,1]
    float* out = (float*)d_out;                 // scalar
    float* ws  = (float*)d_ws;

    hipLaunchKernelGGL(prep_partial, dim3(PREP_BLOCKS), dim3(256), 0, stream, Y, deg, ws);
    hipLaunchKernelGGL(prep_final, dim3(1), dim3(64), 0, stream, ws, out);
    hipLaunchKernelGGL(gap_main, dim3(10, 100), dim3(256), 0, stream, A, Y, ws, out);
}